// Round 10
// baseline (415.002 us; speedup 1.0000x reference)
//
#include <hip/hip_runtime.h>
#include <hip/hip_bf16.h>
#include <stdint.h>

typedef unsigned int uint32;
typedef __attribute__((ext_vector_type(8))) short short8;   // 8 bf16 = 4 VGPRs
typedef __attribute__((ext_vector_type(4))) float float4v;  // MFMA C/D
typedef __attribute__((ext_vector_type(2))) float f32x2;    // packed-f32 accumulate

#define FEAT 128
#define NGRAPH 64
#define GB2  1024    // scatter blocks (4/CU -- R9 lesson: 256 was 1/CU, occupancy-starved)
#define NBK  512     // bucket slots (>= ceil(N/256))
#define QPG  8       // pooling blocks per graph (replicated, atomic-free)

// ---------- bf16 helpers ----------
__device__ __forceinline__ float bf2f_lo(uint32 v) {
    union { uint32 i; float f; } u; u.i = v << 16; return u.f;
}
__device__ __forceinline__ float bf2f_hi(uint32 v) {
    union { uint32 i; float f; } u; u.i = v & 0xffff0000u; return u.f;
}
__device__ __forceinline__ unsigned short f2bf(float f) {
    uint32 u = __builtin_bit_cast(uint32, f);
    uint32 r = (u + 0x7fffu + ((u >> 16) & 1u)) >> 16;      // RNE
    return (unsigned short)r;
}
__device__ __forceinline__ uint32 f2bf2(float lo, float hi) {
    return (uint32)f2bf(lo) | ((uint32)f2bf(hi) << 16);
}

// ---------- bucket scatter, fixed-capacity buckets + folded W swizzle ----------
// cursor[b] is a COUNT (memset 0 on stream); claim = b*CAP + atomicAdd(count,c).
// Blocks >= GB2 do the W1/W2/W3 swizzle (independent work; saves a dispatch).
__global__ void k_bscat2(const int* __restrict__ src, const int* __restrict__ dst,
                         int* __restrict__ cursor, uint32* __restrict__ ebuf, int E,
                         const float* __restrict__ W1, const float* __restrict__ W2,
                         const float* __restrict__ W3, unsigned short* __restrict__ o1,
                         unsigned short* __restrict__ o2, unsigned short* __restrict__ o3,
                         int CAP) {
    int t = threadIdx.x, blk = blockIdx.x;
    if (blk >= GB2) {                        // ---- weight swizzle branch ----
        int b2 = blk - GB2;                  // 0..23: 8 blocks per weight
        int wid = b2 >> 3;
        const float* W = (wid == 0) ? W1 : (wid == 1) ? W2 : W3;
        unsigned short* out = (wid == 0) ? o1 : (wid == 1) ? o2 : o3;
        int e = (b2 & 7) * 256 + t;          // 2048 short8 entries per W
        int kt = e >> 9, ct = (e >> 6) & 7, lane = e & 63;
        int krow = kt * 32 + (lane >> 4) * 8;
        int col = ct * 16 + (lane & 15);
#pragma unroll
        for (int j = 0; j < 8; j++)
            out[e * 8 + j] = f2bf(W[(krow + j) * FEAT + col]);
        return;
    }
    __shared__ int h[NBK];
    __shared__ int cur[NBK];
    for (int b = t; b < NBK; b += 256) h[b] = 0;
    __syncthreads();
    int chunk = (E + GB2 - 1) / GB2;
    int lo = blk * chunk, hi = min(lo + chunk, E);
    for (int e = lo + t; e < hi; e += 256)
        atomicAdd(&h[dst[e] >> 8], 1);
    __syncthreads();
    for (int b = t; b < NBK; b += 256) {
        int c = h[b];
        cur[b] = c ? (b * CAP + atomicAdd(&cursor[b], c)) : 0;
    }
    __syncthreads();
    for (int e = lo + t; e < hi; e += 256) {
        int d = dst[e], s = src[e];
        int p = atomicAdd(&cur[d >> 8], 1);  // LDS atomic
        ebuf[p] = ((uint32)s << 8) | (uint32)(d & 255);
    }
}

// ---------- per-bucket: histogram -> scan -> rowp2/dinv + CSR fill ----------
// Bucket b edges live at [b*CAP, b*CAP + cursor[b]). 512 threads (R9 lesson:
// 256-thr/1.5-block-per-CU was under-occupied; halves per-thread serial work).
__global__ void k_csr2(const uint32* __restrict__ ebuf, const int* __restrict__ cursor,
                       float* __restrict__ dinv, int2* __restrict__ rowp2,
                       int* __restrict__ csrc, int N, int CAP) {
    __shared__ int h[256];
    __shared__ int cur[256];
    int t = threadIdx.x, b = blockIdx.x;     // 512 threads
    int e0 = b * CAP;
    int e1 = e0 + cursor[b];
    if (t < 256) h[t] = 0;
    __syncthreads();
    for (int e = e0 + t; e < e1; e += 512)
        atomicAdd(&h[ebuf[e] & 255u], 1);
    __syncthreads();
    int deg = 0;
    if (t < 256) {
        deg = h[t];
        cur[t] = deg;
    }
    __syncthreads();
    for (int off = 1; off < 256; off <<= 1) {
        int v = 0;
        if (t < 256 && t >= off) v = cur[t - off];
        __syncthreads();
        if (t < 256) cur[t] += v;
        __syncthreads();
    }
    if (t < 256) {
        int r = e0 + cur[t] - deg;           // exclusive within bucket + base
        int node = b * 256 + t;
        if (node < N) {
            rowp2[node] = make_int2(r, r + deg);
            dinv[node] = rsqrtf((float)deg + 1.0f);  // deg = in-deg + self loop
        }
        cur[t] = r;
    }
    __syncthreads();
    for (int e = e0 + t; e < e1; e += 512) {
        uint32 v = ebuf[e];
        int p = atomicAdd(&cur[v & 255u], 1);    // LDS atomic
        csrc[p] = (int)(v >> 8);
    }
}

// ---------- MFMA GEMM: Hb[row] = dinv[row] * (X[row] @ W) ----------
// R4-proven non-persistent form.
template <bool F32IN>
__global__ void k_gemm(const void* __restrict__ Xp,
                       const unsigned short* __restrict__ Wswz,
                       const float* __restrict__ dinv,
                       unsigned short* __restrict__ Hb, int N) {
    __shared__ unsigned short Wl[FEAT * FEAT];              // 32 KB
    {
        const uint4* Wg = (const uint4*)Wswz;
        uint4* Ws = (uint4*)Wl;
        for (int i = threadIdx.x; i < 2048; i += 256) Ws[i] = Wg[i];
    }
    __syncthreads();

    int wave = threadIdx.x >> 6, lane = threadIdx.x & 63;
    int r0 = (blockIdx.x * 4 + wave) * 16;
    if (r0 >= N) return;
    int m = lane & 15, q = lane >> 4;

    int arow = r0 + m; if (arow >= N) arow = N - 1;
    short8 a[4];
    if (F32IN) {
        const float* Ar = (const float*)Xp + (long)arow * FEAT;
#pragma unroll
        for (int kt = 0; kt < 4; kt++) {
            float4 u = *(const float4*)(Ar + kt * 32 + q * 8);
            float4 v = *(const float4*)(Ar + kt * 32 + q * 8 + 4);
            short8 tv;
            tv[0] = (short)f2bf(u.x); tv[1] = (short)f2bf(u.y);
            tv[2] = (short)f2bf(u.z); tv[3] = (short)f2bf(u.w);
            tv[4] = (short)f2bf(v.x); tv[5] = (short)f2bf(v.y);
            tv[6] = (short)f2bf(v.z); tv[7] = (short)f2bf(v.w);
            a[kt] = tv;
        }
    } else {
        const short8* Ar = (const short8*)((const unsigned short*)Xp + (long)arow * FEAT);
#pragma unroll
        for (int kt = 0; kt < 4; kt++) a[kt] = Ar[kt * 4 + q];
    }

    const short8* Bl = (const short8*)Wl;
    float4v acc[8];
#pragma unroll
    for (int ct = 0; ct < 8; ct++) acc[ct] = (float4v){0.f, 0.f, 0.f, 0.f};
#pragma unroll
    for (int ct = 0; ct < 8; ct++) {
        acc[ct] = __builtin_amdgcn_mfma_f32_16x16x32_bf16(Bl[(0 * 8 + ct) * 64 + lane], a[0], acc[ct], 0, 0, 0);
        acc[ct] = __builtin_amdgcn_mfma_f32_16x16x32_bf16(Bl[(1 * 8 + ct) * 64 + lane], a[1], acc[ct], 0, 0, 0);
        acc[ct] = __builtin_amdgcn_mfma_f32_16x16x32_bf16(Bl[(2 * 8 + ct) * 64 + lane], a[2], acc[ct], 0, 0, 0);
        acc[ct] = __builtin_amdgcn_mfma_f32_16x16x32_bf16(Bl[(3 * 8 + ct) * 64 + lane], a[3], acc[ct], 0, 0, 0);
    }

    int node = r0 + m;
    bool ok = (node < N);
    float d = ok ? dinv[node] : 0.f;
#pragma unroll
    for (int ct = 0; ct < 8; ct++) {
        if (ok) {
            uint2 o;
            o.x = f2bf2(acc[ct][0] * d, acc[ct][1] * d);
            o.y = f2bf2(acc[ct][2] * d, acc[ct][3] * d);
            ((uint2*)(Hb + (long)node * FEAT + ct * 16))[q] = o;
        }
    }
}

// ---------- aggregation: OUT[i] = act(dinv_i * (sum_e Hb'[src_e] + Hb'[i]) + b) ----
// R4-proven: quarter-wave FULL-row 256B dwordx4 gathers, f32x2 accumulate,
// zero LDS, no barriers, one row per wave. FETCH ~190MB = 8 XCDs x working set
// (non-coherent private L2s) -- structural floor for random-graph gather.
template <int RELU>
__global__ void k_agg(const uint32* __restrict__ Hb,
                      const int2* __restrict__ rowp2, const int* __restrict__ csrc,
                      const float* __restrict__ dinv, const float* __restrict__ bias,
                      uint32* __restrict__ OUTb, int N) {
    int wave = threadIdx.x >> 6, lane = threadIdx.x & 63;
    int i = blockIdx.x * 4 + wave;
    if (i >= N) return;
    int f = lane & 15, quarter = lane >> 4;
    const uint4* H4 = (const uint4*)Hb;
    f32x2 c0 = {0.f, 0.f}, c1 = c0, c2 = c0, c3 = c0;
    int2 rr = rowp2[i];
    int e0 = rr.x, e1 = rr.y;
    int e = e0;
    for (; e + 16 <= e1; e += 16) {          // 16 edges/iter (4 per quarter)
        int  s[4];
        uint4 h[4];
#pragma unroll
        for (int j = 0; j < 4; j++) s[j] = csrc[e + 4 * j + quarter];
#pragma unroll
        for (int j = 0; j < 4; j++) h[j] = H4[(long)s[j] * 16 + f];
#pragma unroll
        for (int j = 0; j < 4; j++) {
            f32x2 u;
            u.x = bf2f_lo(h[j].x); u.y = bf2f_hi(h[j].x); c0 += u;
            u.x = bf2f_lo(h[j].y); u.y = bf2f_hi(h[j].y); c1 += u;
            u.x = bf2f_lo(h[j].z); u.y = bf2f_hi(h[j].z); c2 += u;
            u.x = bf2f_lo(h[j].w); u.y = bf2f_hi(h[j].w); c3 += u;
        }
    }
    {   // remainder (<16 edges), predicated
        int r = e1 - e;
        int  s[4];
        uint4 h[4];
#pragma unroll
        for (int j = 0; j < 4; j++) {
            int idx = 4 * j + quarter;
            if (idx < r) s[j] = csrc[e + idx];
        }
#pragma unroll
        for (int j = 0; j < 4; j++)
            if (4 * j + quarter < r) h[j] = H4[(long)s[j] * 16 + f];
#pragma unroll
        for (int j = 0; j < 4; j++)
            if (4 * j + quarter < r) {
                f32x2 u;
                u.x = bf2f_lo(h[j].x); u.y = bf2f_hi(h[j].x); c0 += u;
                u.x = bf2f_lo(h[j].y); u.y = bf2f_hi(h[j].y); c1 += u;
                u.x = bf2f_lo(h[j].z); u.y = bf2f_hi(h[j].z); c2 += u;
                u.x = bf2f_lo(h[j].w); u.y = bf2f_hi(h[j].w); c3 += u;
            }
    }
    // combine the 4 quarters
    c0.x += __shfl_xor(c0.x, 16); c0.y += __shfl_xor(c0.y, 16);
    c1.x += __shfl_xor(c1.x, 16); c1.y += __shfl_xor(c1.y, 16);
    c2.x += __shfl_xor(c2.x, 16); c2.y += __shfl_xor(c2.y, 16);
    c3.x += __shfl_xor(c3.x, 16); c3.y += __shfl_xor(c3.y, 16);
    c0.x += __shfl_xor(c0.x, 32); c0.y += __shfl_xor(c0.y, 32);
    c1.x += __shfl_xor(c1.x, 32); c1.y += __shfl_xor(c1.y, 32);
    c2.x += __shfl_xor(c2.x, 32); c2.y += __shfl_xor(c2.y, 32);
    c3.x += __shfl_xor(c3.x, 32); c3.y += __shfl_xor(c3.y, 32);
    if (quarter == 0) {
        uint4 hv = H4[(long)i * 16 + f];     // self term (already dinv-scaled)
        c0.x += bf2f_lo(hv.x); c0.y += bf2f_hi(hv.x);
        c1.x += bf2f_lo(hv.y); c1.y += bf2f_hi(hv.y);
        c2.x += bf2f_lo(hv.z); c2.y += bf2f_hi(hv.z);
        c3.x += bf2f_lo(hv.w); c3.y += bf2f_hi(hv.w);
        float di = dinv[i];
        const float4* b4 = (const float4*)bias;
        float4 bb0 = b4[2 * f], bb1 = b4[2 * f + 1];
        c0.x = c0.x * di + bb0.x; c0.y = c0.y * di + bb0.y;
        c1.x = c1.x * di + bb0.z; c1.y = c1.y * di + bb0.w;
        c2.x = c2.x * di + bb1.x; c2.y = c2.y * di + bb1.y;
        c3.x = c3.x * di + bb1.z; c3.y = c3.y * di + bb1.w;
        if (RELU) {
            c0.x = fmaxf(c0.x, 0.f); c0.y = fmaxf(c0.y, 0.f);
            c1.x = fmaxf(c1.x, 0.f); c1.y = fmaxf(c1.y, 0.f);
            c2.x = fmaxf(c2.x, 0.f); c2.y = fmaxf(c2.y, 0.f);
            c3.x = fmaxf(c3.x, 0.f); c3.y = fmaxf(c3.y, 0.f);
        }
        uint4 o;
        o.x = f2bf2(c0.x, c0.y);
        o.y = f2bf2(c1.x, c1.y);
        o.z = f2bf2(c2.x, c2.y);
        o.w = f2bf2(c3.x, c3.y);
        ((uint4*)OUTb)[(long)i * 16 + f] = o;
    }
}

// ---------- pooling: atomic-free segmented sum (R6-proven, 512 blocks) ----------
__global__ void k_pool2(const uint32* __restrict__ Gb, const int* __restrict__ batch,
                        float* __restrict__ pool, int N) {
    __shared__ float spx[256], spy[256];
    int t = threadIdx.x;
    int g = blockIdx.x >> 3, qtr = blockIdx.x & (QPG - 1);
    int lo, hi;
    { int l = 0, h = N; while (l < h) { int m = (l + h) >> 1; if (batch[m] < g) l = m + 1; else h = m; } lo = l; }
    { int l = lo, h = N; while (l < h) { int m = (l + h) >> 1; if (batch[m] < g + 1) l = m + 1; else h = m; } hi = l; }
    int cnt = hi - lo;
    int chunk = (cnt + QPG - 1) / QPG;
    int lo2 = lo + qtr * chunk;
    int hi2 = min(lo2 + chunk, hi);
    int f = t & 63, sub = t >> 6;
    float ax = 0.f, ay = 0.f;
#pragma unroll 4
    for (int i = lo2 + sub; i < hi2; i += 4) {
        uint32 v = Gb[(long)i * 64 + f];
        ax += bf2f_lo(v); ay += bf2f_hi(v);
    }
    spx[t] = ax; spy[t] = ay;
    __syncthreads();
    if (t < 64) {
        float sx = spx[t] + spx[t + 64] + spx[t + 128] + spx[t + 192];
        float sy = spy[t] + spy[t + 64] + spy[t + 128] + spy[t + 192];
        float* pr = pool + ((size_t)qtr * NGRAPH + g) * FEAT;
        pr[2 * t]     = sx;
        pr[2 * t + 1] = sy;
    }
}

// ---------- head: sum QPG replicas; counts via binary search on sorted batch ----------
__global__ void k_final(const float* __restrict__ pool, const int* __restrict__ batch,
                        const float* __restrict__ Wlin, const float* __restrict__ blin,
                        float* __restrict__ out, int N) {
    __shared__ float es[FEAT];
    __shared__ int lohi[2];
    int g = blockIdx.x, t = threadIdx.x;     // 128 threads
    if (t < 2) {
        int key = g + t;
        int lo = 0, hi = N;
        while (lo < hi) {
            int mid = (lo + hi) >> 1;
            if (batch[mid] < key) lo = mid + 1; else hi = mid;
        }
        lohi[t] = lo;
    }
    float s = 0.f;
#pragma unroll
    for (int r = 0; r < QPG; r++) s += pool[(r * NGRAPH + g) * FEAT + t];
    __syncthreads();
    float c = (float)max(lohi[1] - lohi[0], 1);
    float e = s / c;
    es[t] = e;
    out[NGRAPH * 10 + g * FEAT + t] = e;
    __syncthreads();
    if (t < 10) {
        float a = blin[t];
        for (int k = 0; k < FEAT; k++)
            a += es[k] * Wlin[k * 10 + t];
        out[g * 10 + t] = a;
    }
}

// ---------------------------------------------------------------
extern "C" void kernel_launch(void* const* d_in, const int* in_sizes, int n_in,
                              void* d_out, int out_size, void* d_ws, size_t ws_size,
                              hipStream_t stream) {
    const float* x    = (const float*)d_in[0];
    const int*   ei   = (const int*)d_in[1];
    const int*   batch= (const int*)d_in[2];
    const float* W1   = (const float*)d_in[3];
    const float* b1   = (const float*)d_in[4];
    const float* W2   = (const float*)d_in[5];
    const float* b2   = (const float*)d_in[6];
    const float* W3   = (const float*)d_in[7];
    const float* b3   = (const float*)d_in[8];
    const float* Wlin = (const float*)d_in[9];
    const float* blin = (const float*)d_in[10];

    const int N = in_sizes[2];
    const int E = in_sizes[1] / 2;
    const int* src = ei;
    const int* dst = ei + E;
    const int NB = (N + 255) >> 8;           // buckets used (<= NBK)
    // fixed bucket capacity: 2x mean, rounded up to 256 (>= +60 sigma; overflow ~0)
    int CAP = ((E * 2 / (NB > 0 ? NB : 1)) + 255) & ~255;
    if (CAP < 1024) CAP = 1024;

    // ---- workspace carve ----
    char* w = (char*)d_ws;
    auto take = [&](size_t bytes) {
        char* p = w;
        w += (bytes + 255) & ~(size_t)255;
        return p;
    };
    float*  dinv   = (float*) take((size_t)N * 4);
    int2*   rowp2  = (int2*)  take((size_t)N * 8);
    int*    csrc   = (int*)   take((size_t)NB * CAP * 4);
    uint32* ebuf   = (uint32*)take((size_t)NB * CAP * 4);
    int*    cursor = (int*)   take((size_t)NBK * 4);
    uint32* hbuf   = (uint32*)take((size_t)N * FEAT * 2);   // B0
    uint32* gbuf   = (uint32*)take((size_t)N * FEAT * 2);   // B1
    unsigned short* w1s = (unsigned short*)take(FEAT * FEAT * 2);
    unsigned short* w2s = (unsigned short*)take(FEAT * FEAT * 2);
    unsigned short* w3s = (unsigned short*)take(FEAT * FEAT * 2);
    float*  pool   = (float*) take((size_t)QPG * NGRAPH * FEAT * 4);   // 256 KB replicas
    (void)ws_size; (void)n_in; (void)out_size;

    // --- CSR build: cursor=counts (memset) -> scatter(+swizzle) -> per-bucket CSR ---
    hipMemsetAsync(cursor, 0, NBK * sizeof(int), stream);
    k_bscat2<<<GB2 + 24, 256, 0, stream>>>(src, dst, cursor, ebuf, E,
                                           W1, W2, W3, w1s, w2s, w3s, CAP);
    k_csr2  <<<NB, 512, 0, stream>>>(ebuf, cursor, dinv, rowp2, csrc, N, CAP);

    const int tile_blocks = (N + 63) / 64;
    const int agg_blocks  = (N + 3) / 4;

    // layer 1
    k_gemm<true> <<<tile_blocks, 256, 0, stream>>>(x, w1s, dinv, (unsigned short*)hbuf, N);
    k_agg<1><<<agg_blocks, 256, 0, stream>>>(hbuf, rowp2, csrc, dinv, b1, gbuf, N);
    // layer 2
    k_gemm<false><<<tile_blocks, 256, 0, stream>>>(gbuf, w2s, dinv, (unsigned short*)hbuf, N);
    k_agg<1><<<agg_blocks, 256, 0, stream>>>(hbuf, rowp2, csrc, dinv, b2, gbuf, N);
    // layer 3 (no relu)
    k_gemm<false><<<tile_blocks, 256, 0, stream>>>(gbuf, w3s, dinv, (unsigned short*)hbuf, N);
    k_agg<0><<<agg_blocks, 256, 0, stream>>>(hbuf, rowp2, csrc, dinv, b3, gbuf, N);

    // pooling (atomic-free, 512 blocks) + head
    k_pool2<<<NGRAPH * QPG, 256, 0, stream>>>(gbuf, batch, pool, N);
    k_final<<<NGRAPH, 128, 0, stream>>>(pool, batch, Wlin, blin, (float*)d_out, N);
}

// Round 11
// 393.949 us; speedup vs baseline: 1.0534x; 1.0534x over previous
//
#include <hip/hip_runtime.h>
#include <hip/hip_bf16.h>
#include <stdint.h>

typedef unsigned int uint32;
typedef __attribute__((ext_vector_type(8))) short short8;   // 8 bf16 = 4 VGPRs
typedef __attribute__((ext_vector_type(4))) float float4v;  // MFMA C/D
typedef __attribute__((ext_vector_type(2))) float f32x2;    // packed-f32 accumulate

#define FEAT 128
#define NGRAPH 64
#define GB   256     // scatter blocks
#define NBK  512     // bucket slots (>= ceil(N/256))

// ---------- bf16 helpers ----------
__device__ __forceinline__ float bf2f_lo(uint32 v) {
    union { uint32 i; float f; } u; u.i = v << 16; return u.f;
}
__device__ __forceinline__ float bf2f_hi(uint32 v) {
    union { uint32 i; float f; } u; u.i = v & 0xffff0000u; return u.f;
}
__device__ __forceinline__ unsigned short f2bf(float f) {
    uint32 u = __builtin_bit_cast(uint32, f);
    uint32 r = (u + 0x7fffu + ((u >> 16) & 1u)) >> 16;      // RNE
    return (unsigned short)r;
}
__device__ __forceinline__ uint32 f2bf2(float lo, float hi) {
    return (uint32)f2bf(lo) | ((uint32)f2bf(hi) << 16);
}

// ---------- W swizzle (24 blocks; block 0 also inits bucket cursors) ----------
__global__ void k_wswz(const float* __restrict__ W1, const float* __restrict__ W2,
                       const float* __restrict__ W3, unsigned short* __restrict__ o1,
                       unsigned short* __restrict__ o2, unsigned short* __restrict__ o3,
                       int* __restrict__ cursor, int CAP) {
    int t = threadIdx.x, blk = blockIdx.x;
    if (blk == 0)
        for (int b = t; b < NBK; b += 256) cursor[b] = b * CAP;
    int wid = blk >> 3;
    const float* W = (wid == 0) ? W1 : (wid == 1) ? W2 : W3;
    unsigned short* out = (wid == 0) ? o1 : (wid == 1) ? o2 : o3;
    int e = (blk & 7) * 256 + t;             // 2048 short8 entries per W
    int kt = e >> 9, ct = (e >> 6) & 7, lane = e & 63;
    int krow = kt * 32 + (lane >> 4) * 8;
    int col = ct * 16 + (lane & 15);
#pragma unroll
    for (int j = 0; j < 8; j++)
        out[e * 8 + j] = f2bf(W[(krow + j) * FEAT + col]);
}

// ---------- bucket scatter with FIXED-CAPACITY buckets ----------
// Bucket b owns ebuf[b*CAP, (b+1)*CAP). CAP = 2x mean (+64 sigma) -> overflow
// probability ~0. Each block histograms its chunk in LDS, claims a contiguous
// range per bucket with ONE global atomicAdd, then scatters. Order within a
// bucket is arbitrary (sums are order-independent). 256 blocks: larger chunks
// give longer per-bucket write runs (R10 lesson: 1024 blocks regressed).
__global__ void k_bscat2(const int* __restrict__ src, const int* __restrict__ dst,
                         int* __restrict__ cursor, uint32* __restrict__ ebuf, int E) {
    __shared__ int h[NBK];
    __shared__ int cur[NBK];
    int t = threadIdx.x, blk = blockIdx.x;
    for (int b = t; b < NBK; b += 256) h[b] = 0;
    __syncthreads();
    int chunk = (E + GB - 1) / GB;
    int lo = blk * chunk, hi = min(lo + chunk, E);
    for (int e = lo + t; e < hi; e += 256)
        atomicAdd(&h[dst[e] >> 8], 1);
    __syncthreads();
    for (int b = t; b < NBK; b += 256) {
        int c = h[b];
        cur[b] = c ? atomicAdd(&cursor[b], c) : 0;
    }
    __syncthreads();
    for (int e = lo + t; e < hi; e += 256) {
        int d = dst[e], s = src[e];
        int p = atomicAdd(&cur[d >> 8], 1);  // LDS atomic
        ebuf[p] = ((uint32)s << 8) | (uint32)(d & 255);
    }
}

// ---------- per-bucket: histogram -> scan -> rowp2/dinv + CSR fill ----------
// Bucket b edges live at [b*CAP, cursor[b]) (cursor ended at base+count).
__global__ void k_csr2(const uint32* __restrict__ ebuf, const int* __restrict__ cursor,
                       float* __restrict__ dinv, int2* __restrict__ rowp2,
                       int* __restrict__ csrc, int N, int CAP) {
    __shared__ int h[256];
    __shared__ int cur[256];
    int t = threadIdx.x, b = blockIdx.x;
    int e0 = b * CAP;
    int e1 = cursor[b];
    h[t] = 0;
    __syncthreads();
    for (int e = e0 + t; e < e1; e += 256)
        atomicAdd(&h[ebuf[e] & 255u], 1);
    __syncthreads();
    int deg = h[t];
    cur[t] = deg;
    __syncthreads();
    for (int off = 1; off < 256; off <<= 1) {
        int v = (t >= off) ? cur[t - off] : 0;
        __syncthreads();
        cur[t] += v;
        __syncthreads();
    }
    int r = e0 + cur[t] - deg;               // exclusive within bucket + base
    int node = b * 256 + t;
    if (node < N) {
        rowp2[node] = make_int2(r, r + deg);
        dinv[node] = rsqrtf((float)deg + 1.0f);  // deg = in-deg + self loop
    }
    cur[t] = r;
    __syncthreads();
    for (int e = e0 + t; e < e1; e += 256) {
        uint32 v = ebuf[e];
        int p = atomicAdd(&cur[v & 255u], 1);    // LDS atomic
        csrc[p] = (int)(v >> 8);
    }
}

// ---------- MFMA GEMM: Hb[row] = dinv[row] * (X[row] @ W) ----------
// R4-proven non-persistent form.
template <bool F32IN>
__global__ void k_gemm(const void* __restrict__ Xp,
                       const unsigned short* __restrict__ Wswz,
                       const float* __restrict__ dinv,
                       unsigned short* __restrict__ Hb, int N) {
    __shared__ unsigned short Wl[FEAT * FEAT];              // 32 KB
    {
        const uint4* Wg = (const uint4*)Wswz;
        uint4* Ws = (uint4*)Wl;
        for (int i = threadIdx.x; i < 2048; i += 256) Ws[i] = Wg[i];
    }
    __syncthreads();

    int wave = threadIdx.x >> 6, lane = threadIdx.x & 63;
    int r0 = (blockIdx.x * 4 + wave) * 16;
    if (r0 >= N) return;
    int m = lane & 15, q = lane >> 4;

    int arow = r0 + m; if (arow >= N) arow = N - 1;
    short8 a[4];
    if (F32IN) {
        const float* Ar = (const float*)Xp + (long)arow * FEAT;
#pragma unroll
        for (int kt = 0; kt < 4; kt++) {
            float4 u = *(const float4*)(Ar + kt * 32 + q * 8);
            float4 v = *(const float4*)(Ar + kt * 32 + q * 8 + 4);
            short8 tv;
            tv[0] = (short)f2bf(u.x); tv[1] = (short)f2bf(u.y);
            tv[2] = (short)f2bf(u.z); tv[3] = (short)f2bf(u.w);
            tv[4] = (short)f2bf(v.x); tv[5] = (short)f2bf(v.y);
            tv[6] = (short)f2bf(v.z); tv[7] = (short)f2bf(v.w);
            a[kt] = tv;
        }
    } else {
        const short8* Ar = (const short8*)((const unsigned short*)Xp + (long)arow * FEAT);
#pragma unroll
        for (int kt = 0; kt < 4; kt++) a[kt] = Ar[kt * 4 + q];
    }

    const short8* Bl = (const short8*)Wl;
    float4v acc[8];
#pragma unroll
    for (int ct = 0; ct < 8; ct++) acc[ct] = (float4v){0.f, 0.f, 0.f, 0.f};
#pragma unroll
    for (int ct = 0; ct < 8; ct++) {
        acc[ct] = __builtin_amdgcn_mfma_f32_16x16x32_bf16(Bl[(0 * 8 + ct) * 64 + lane], a[0], acc[ct], 0, 0, 0);
        acc[ct] = __builtin_amdgcn_mfma_f32_16x16x32_bf16(Bl[(1 * 8 + ct) * 64 + lane], a[1], acc[ct], 0, 0, 0);
        acc[ct] = __builtin_amdgcn_mfma_f32_16x16x32_bf16(Bl[(2 * 8 + ct) * 64 + lane], a[2], acc[ct], 0, 0, 0);
        acc[ct] = __builtin_amdgcn_mfma_f32_16x16x32_bf16(Bl[(3 * 8 + ct) * 64 + lane], a[3], acc[ct], 0, 0, 0);
    }

    int node = r0 + m;
    bool ok = (node < N);
    float d = ok ? dinv[node] : 0.f;
#pragma unroll
    for (int ct = 0; ct < 8; ct++) {
        if (ok) {
            uint2 o;
            o.x = f2bf2(acc[ct][0] * d, acc[ct][1] * d);
            o.y = f2bf2(acc[ct][2] * d, acc[ct][3] * d);
            ((uint2*)(Hb + (long)node * FEAT + ct * 16))[q] = o;
        }
    }
}

// ---------- aggregation: OUT[i] = act(dinv_i * (sum_e Hb'[src_e] + Hb'[i]) + b) ----
// R4-proven: quarter-wave FULL-row 256B dwordx4 gathers, f32x2 accumulate,
// zero LDS, no barriers, one row per wave (continuous backfill). FETCH ~190MB
// = 8 XCDs x working set (non-coherent private L2s) -- structural floor.
template <int RELU>
__global__ void k_agg(const uint32* __restrict__ Hb,
                      const int2* __restrict__ rowp2, const int* __restrict__ csrc,
                      const float* __restrict__ dinv, const float* __restrict__ bias,
                      uint32* __restrict__ OUTb, int N) {
    int wave = threadIdx.x >> 6, lane = threadIdx.x & 63;
    int i = blockIdx.x * 4 + wave;
    if (i >= N) return;
    int f = lane & 15, quarter = lane >> 4;
    const uint4* H4 = (const uint4*)Hb;
    f32x2 c0 = {0.f, 0.f}, c1 = c0, c2 = c0, c3 = c0;
    int2 rr = rowp2[i];
    int e0 = rr.x, e1 = rr.y;
    int e = e0;
    for (; e + 16 <= e1; e += 16) {          // 16 edges/iter (4 per quarter)
        int  s[4];
        uint4 h[4];
#pragma unroll
        for (int j = 0; j < 4; j++) s[j] = csrc[e + 4 * j + quarter];
#pragma unroll
        for (int j = 0; j < 4; j++) h[j] = H4[(long)s[j] * 16 + f];
#pragma unroll
        for (int j = 0; j < 4; j++) {
            f32x2 u;
            u.x = bf2f_lo(h[j].x); u.y = bf2f_hi(h[j].x); c0 += u;
            u.x = bf2f_lo(h[j].y); u.y = bf2f_hi(h[j].y); c1 += u;
            u.x = bf2f_lo(h[j].z); u.y = bf2f_hi(h[j].z); c2 += u;
            u.x = bf2f_lo(h[j].w); u.y = bf2f_hi(h[j].w); c3 += u;
        }
    }
    {   // remainder (<16 edges), predicated
        int r = e1 - e;
        int  s[4];
        uint4 h[4];
#pragma unroll
        for (int j = 0; j < 4; j++) {
            int idx = 4 * j + quarter;
            if (idx < r) s[j] = csrc[e + idx];
        }
#pragma unroll
        for (int j = 0; j < 4; j++)
            if (4 * j + quarter < r) h[j] = H4[(long)s[j] * 16 + f];
#pragma unroll
        for (int j = 0; j < 4; j++)
            if (4 * j + quarter < r) {
                f32x2 u;
                u.x = bf2f_lo(h[j].x); u.y = bf2f_hi(h[j].x); c0 += u;
                u.x = bf2f_lo(h[j].y); u.y = bf2f_hi(h[j].y); c1 += u;
                u.x = bf2f_lo(h[j].z); u.y = bf2f_hi(h[j].z); c2 += u;
                u.x = bf2f_lo(h[j].w); u.y = bf2f_hi(h[j].w); c3 += u;
            }
    }
    // combine the 4 quarters
    c0.x += __shfl_xor(c0.x, 16); c0.y += __shfl_xor(c0.y, 16);
    c1.x += __shfl_xor(c1.x, 16); c1.y += __shfl_xor(c1.y, 16);
    c2.x += __shfl_xor(c2.x, 16); c2.y += __shfl_xor(c2.y, 16);
    c3.x += __shfl_xor(c3.x, 16); c3.y += __shfl_xor(c3.y, 16);
    c0.x += __shfl_xor(c0.x, 32); c0.y += __shfl_xor(c0.y, 32);
    c1.x += __shfl_xor(c1.x, 32); c1.y += __shfl_xor(c1.y, 32);
    c2.x += __shfl_xor(c2.x, 32); c2.y += __shfl_xor(c2.y, 32);
    c3.x += __shfl_xor(c3.x, 32); c3.y += __shfl_xor(c3.y, 32);
    if (quarter == 0) {
        uint4 hv = H4[(long)i * 16 + f];     // self term (already dinv-scaled)
        c0.x += bf2f_lo(hv.x); c0.y += bf2f_hi(hv.x);
        c1.x += bf2f_lo(hv.y); c1.y += bf2f_hi(hv.y);
        c2.x += bf2f_lo(hv.z); c2.y += bf2f_hi(hv.z);
        c3.x += bf2f_lo(hv.w); c3.y += bf2f_hi(hv.w);
        float di = dinv[i];
        const float4* b4 = (const float4*)bias;
        float4 bb0 = b4[2 * f], bb1 = b4[2 * f + 1];
        c0.x = c0.x * di + bb0.x; c0.y = c0.y * di + bb0.y;
        c1.x = c1.x * di + bb0.z; c1.y = c1.y * di + bb0.w;
        c2.x = c2.x * di + bb1.x; c2.y = c2.y * di + bb1.y;
        c3.x = c3.x * di + bb1.z; c3.y = c3.y * di + bb1.w;
        if (RELU) {
            c0.x = fmaxf(c0.x, 0.f); c0.y = fmaxf(c0.y, 0.f);
            c1.x = fmaxf(c1.x, 0.f); c1.y = fmaxf(c1.y, 0.f);
            c2.x = fmaxf(c2.x, 0.f); c2.y = fmaxf(c2.y, 0.f);
            c3.x = fmaxf(c3.x, 0.f); c3.y = fmaxf(c3.y, 0.f);
        }
        uint4 o;
        o.x = f2bf2(c0.x, c0.y);
        o.y = f2bf2(c1.x, c1.y);
        o.z = f2bf2(c2.x, c2.y);
        o.w = f2bf2(c3.x, c3.y);
        ((uint4*)OUTb)[(long)i * 16 + f] = o;
    }
}

// ---------- pooling + head fused: one block per graph, 1024 threads ----------
// 16 row-subsets x 64 feat-pairs stream the graph's rows coalesced; LDS reduce;
// mean + emb write + 10-class head in the same block. (R9-measured best tail.)
__global__ void k_pf(const uint32* __restrict__ Gb, const int* __restrict__ batch,
                     const float* __restrict__ Wlin, const float* __restrict__ blin,
                     float* __restrict__ out, int N) {
    __shared__ float spx[1024], spy[1024];
    __shared__ float es[FEAT];
    int t = threadIdx.x, g = blockIdx.x;
    int lo, hi;
    { int l = 0, h = N; while (l < h) { int m = (l + h) >> 1; if (batch[m] < g) l = m + 1; else h = m; } lo = l; }
    { int l = lo, h = N; while (l < h) { int m = (l + h) >> 1; if (batch[m] < g + 1) l = m + 1; else h = m; } hi = l; }
    int f = t & 63, sub = t >> 6;            // 16 row subsets
    float ax = 0.f, ay = 0.f;
#pragma unroll 4
    for (int i = lo + sub; i < hi; i += 16) {
        uint32 v = Gb[(long)i * 64 + f];
        ax += bf2f_lo(v); ay += bf2f_hi(v);
    }
    spx[t] = ax; spy[t] = ay;
    __syncthreads();
    if (t < 64) {
        float sx = 0.f, sy = 0.f;
#pragma unroll
        for (int r = 0; r < 16; r++) { sx += spx[t + 64 * r]; sy += spy[t + 64 * r]; }
        float c = (float)max(hi - lo, 1);
        float e0 = sx / c, e1 = sy / c;
        es[2 * t] = e0; es[2 * t + 1] = e1;
        out[NGRAPH * 10 + g * FEAT + 2 * t]     = e0;
        out[NGRAPH * 10 + g * FEAT + 2 * t + 1] = e1;
    }
    __syncthreads();
    if (t < 10) {
        float a = blin[t];
        for (int k = 0; k < FEAT; k++)
            a += es[k] * Wlin[k * 10 + t];
        out[g * 10 + t] = a;
    }
}

// ---------------------------------------------------------------
extern "C" void kernel_launch(void* const* d_in, const int* in_sizes, int n_in,
                              void* d_out, int out_size, void* d_ws, size_t ws_size,
                              hipStream_t stream) {
    const float* x    = (const float*)d_in[0];
    const int*   ei   = (const int*)d_in[1];
    const int*   batch= (const int*)d_in[2];
    const float* W1   = (const float*)d_in[3];
    const float* b1   = (const float*)d_in[4];
    const float* W2   = (const float*)d_in[5];
    const float* b2   = (const float*)d_in[6];
    const float* W3   = (const float*)d_in[7];
    const float* b3   = (const float*)d_in[8];
    const float* Wlin = (const float*)d_in[9];
    const float* blin = (const float*)d_in[10];

    const int N = in_sizes[2];
    const int E = in_sizes[1] / 2;
    const int* src = ei;
    const int* dst = ei + E;
    const int NB = (N + 255) >> 8;           // buckets used (<= NBK)
    // fixed bucket capacity: 2x mean, rounded up to 256 (>= +60 sigma; overflow ~0)
    int CAP = ((E * 2 / (NB > 0 ? NB : 1)) + 255) & ~255;
    if (CAP < 1024) CAP = 1024;

    // ---- workspace carve ----
    char* w = (char*)d_ws;
    auto take = [&](size_t bytes) {
        char* p = w;
        w += (bytes + 255) & ~(size_t)255;
        return p;
    };
    float*  dinv   = (float*) take((size_t)N * 4);
    int2*   rowp2  = (int2*)  take((size_t)N * 8);
    int*    csrc   = (int*)   take((size_t)NB * CAP * 4);
    uint32* ebuf   = (uint32*)take((size_t)NB * CAP * 4);
    int*    cursor = (int*)   take((size_t)NBK * 4);
    uint32* hbuf   = (uint32*)take((size_t)N * FEAT * 2);   // B0
    uint32* gbuf   = (uint32*)take((size_t)N * FEAT * 2);   // B1
    unsigned short* w1s = (unsigned short*)take(FEAT * FEAT * 2);
    unsigned short* w2s = (unsigned short*)take(FEAT * FEAT * 2);
    unsigned short* w3s = (unsigned short*)take(FEAT * FEAT * 2);
    (void)ws_size; (void)n_in; (void)out_size;

    // --- CSR build: swizzle+cursor-init -> fixed-cap scatter -> per-bucket CSR ---
    k_wswz  <<<24, 256, 0, stream>>>(W1, W2, W3, w1s, w2s, w3s, cursor, CAP);
    k_bscat2<<<GB, 256, 0, stream>>>(src, dst, cursor, ebuf, E);
    k_csr2  <<<NB, 256, 0, stream>>>(ebuf, cursor, dinv, rowp2, csrc, N, CAP);

    const int tile_blocks = (N + 63) / 64;
    const int agg_blocks  = (N + 3) / 4;

    // layer 1
    k_gemm<true> <<<tile_blocks, 256, 0, stream>>>(x, w1s, dinv, (unsigned short*)hbuf, N);
    k_agg<1><<<agg_blocks, 256, 0, stream>>>(hbuf, rowp2, csrc, dinv, b1, gbuf, N);
    // layer 2
    k_gemm<false><<<tile_blocks, 256, 0, stream>>>(gbuf, w2s, dinv, (unsigned short*)hbuf, N);
    k_agg<1><<<agg_blocks, 256, 0, stream>>>(hbuf, rowp2, csrc, dinv, b2, gbuf, N);
    // layer 3 (no relu)
    k_gemm<false><<<tile_blocks, 256, 0, stream>>>(gbuf, w3s, dinv, (unsigned short*)hbuf, N);
    k_agg<0><<<agg_blocks, 256, 0, stream>>>(hbuf, rowp2, csrc, dinv, b3, gbuf, N);

    // pooling + head (fused)
    k_pf<<<NGRAPH, 1024, 0, stream>>>(gbuf, batch, Wlin, blin, (float*)d_out, N);
}